// Round 12
// baseline (230.873 us; speedup 1.0000x reference)
//
#include <hip/hip_runtime.h>
#include <hip/hip_bf16.h>
#include <math.h>

#define BATCH 32
#define WLEN  2048
#define NBLK  256   // 8 w-tiles x 32 batches

typedef __attribute__((ext_vector_type(8))) short short8;
typedef __attribute__((ext_vector_type(4))) short short4v;
typedef __attribute__((ext_vector_type(4))) float floatx4;

__device__ inline short f2bf(float f) {
  unsigned u = __float_as_uint(f);
  unsigned r = (u + 0x7fffu + ((u >> 16) & 1u)) >> 16;
  return (short)r;
}

// ---------------------------------------------------------------------------
// Single fused kernel. Grid (8, 32) x 512 thr; 2 blocks/CU capacity (2x the
// grid) so all 256 blocks are co-resident -> bounded spin on device-scope
// counters is safe. Each block owns out cols [w0, w0+256) of one batch and
// recomputes y1 halo locally; y1 never touches HBM.
//   A: stage x (274 cols, bf16) + routing1 partial; blocks<24 pack w2,
//      blocks 24..35 pack w1; post ctr1; spin1.
//   B: r1; conv1 MFMA (17 col-chunks x 2 o-halves as 34 wave-tasks), epilogue
//      held in regs; barrier; y1 -> LDS (aliased over x); routing2 partial;
//      post ctr2.
//   C: conv2 MFMA pass 0 (cols 0..63 of wave's 128); spin2; r2; epilogue+pool;
//      pass 1; done.
// ---------------------------------------------------------------------------
__global__ __launch_bounds__(512, 4) void fused_all(
    const float* __restrict__ x,
    const float* __restrict__ w1, const float* __restrict__ b1,
    const float* __restrict__ fcw1, const float* __restrict__ fcb1,
    const float* __restrict__ g1, const float* __restrict__ be1,
    const float* __restrict__ rm1, const float* __restrict__ rv1,
    const float* __restrict__ w2, const float* __restrict__ b2,
    const float* __restrict__ fcw2, const float* __restrict__ fcb2,
    const float* __restrict__ g2, const float* __restrict__ be2,
    const float* __restrict__ rm2, const float* __restrict__ rv2,
    short* __restrict__ wp1, short* __restrict__ wp2,
    float* __restrict__ racc1, float* __restrict__ racc2,
    int* __restrict__ ctrs, float* __restrict__ out) {
  const int jt = blockIdx.x;        // 0..7
  const int b  = blockIdx.y;        // 0..31
  const int bid = b * 8 + jt;
  const int w0 = jt * 256;
  const int tid = threadIdx.x;
  const int wave = tid >> 6, lane = tid & 63;
  const int ln = lane & 15, kg = lane >> 4;

  // ybuf aliases: phase A/B-read = xs[8 ig][274 p][8 e]  (p <-> w = w0-9+p)
  //               phase B-write/C = y1s[16 ig][272 yc][8 e] (yc <-> w = w0-8+yc)
  __shared__ short ybuf[16 * 272 * 8];   // 69632 B
  __shared__ float red[512];             // 2048 B

  // ---------------- phase A: stage x + routing1 partial ----------------
  {
    const float* xb = x + (size_t)b * 64 * WLEN;
    float rsum = 0.f;
    for (int idx = tid; idx < 8 * 274; idx += 512) {
      int ig = idx / 274;
      int p = idx - ig * 274;
      int w = w0 - 9 + p;
      short8 v = {0, 0, 0, 0, 0, 0, 0, 0};
      if ((unsigned)w < (unsigned)WLEN) {
        const float* src = xb + (size_t)(ig * 8) * WLEN + w;
        float fv[8];
#pragma unroll
        for (int e = 0; e < 8; ++e) fv[e] = src[(size_t)e * WLEN];
#pragma unroll
        for (int e = 0; e < 8; ++e) v[e] = f2bf(fv[e]);
        if (p >= 9 && p < 265) {
#pragma unroll
          for (int e = 0; e < 8; ++e) rsum += fv[e] * fcw1[ig * 8 + e];
        }
      }
      *(short8*)(ybuf + (size_t)idx * 8) = v;
    }

    // side jobs: pack weights (done before counter post)
    if (bid < 24) {            // w2 -> wp2[k][ig16][o256][8], 12288 items
      int iw = bid * 512 + tid;
      int o = iw & 255;
      int t = iw >> 8;
      int ig = t & 15;
      int k = t >> 4;
      short8 v;
#pragma unroll
      for (int e = 0; e < 8; ++e) v[e] = f2bf(w2[(o * 128 + ig * 8 + e) * 3 + k]);
      *(short8*)(wp2 + (size_t)iw * 8) = v;
    } else if (bid < 36 && tid < 256) {  // w1 -> wp1[k][ig8][o128][8], 3072
      int iw = (bid - 24) * 256 + tid;
      int o = iw & 127;
      int t = iw >> 7;
      int ig = t & 7;
      int k = t >> 3;
      short8 v;
#pragma unroll
      for (int e = 0; e < 8; ++e) v[e] = f2bf(w1[(o * 64 + ig * 8 + e) * 3 + k]);
      *(short8*)(wp1 + (size_t)iw * 8) = v;
    }

    red[tid] = rsum;
    __syncthreads();
    for (int s = 256; s > 0; s >>= 1) {
      if (tid < s) red[tid] += red[tid + s];
      __syncthreads();
    }
    if (tid == 0) {
      atomicExch(&racc1[bid], red[0]);
      __threadfence();
      atomicAdd(&ctrs[0], 1);
      // bounded spin (bails after ~2e6 polls -> wrong answer, never a hang)
      for (int it = 0; it < 2000000; ++it)
        if (atomicAdd(&ctrs[0], 0) >= NBLK) break;
    }
    __syncthreads();
    __threadfence();
  }

  // ---------------- phase B: conv1 ----------------
  float rsum2 = 0.f;
  {
    float zs = 0.f;
#pragma unroll
    for (int t = 0; t < 8; ++t) zs += atomicAdd(&racc1[b * 8 + t], 0.0f);
    float z = zs * (1.f / (float)WLEN) + fcb1[0];
    float r1v = 1.f / (1.f + expf(-z));

    short4v held[5][4];
#pragma unroll
    for (int i = 0; i < 5; ++i) {
      int t = wave + i * 8;
      if (t < 34) {
        const int oh = t & 1, ck = t >> 1;
        floatx4 acc[4];
#pragma unroll
        for (int ms = 0; ms < 4; ++ms) acc[ms] = (floatx4){0.f, 0.f, 0.f, 0.f};
#pragma unroll
        for (int q = 0; q < 2; ++q) {
#pragma unroll
          for (int k = 0; k < 3; ++k) {
            short8 af[4];
            const short* wk =
                wp1 + ((size_t)(k * 8 + q * 4 + kg) * 128 + oh * 64 + ln) * 8;
#pragma unroll
            for (int ms = 0; ms < 4; ++ms)
              af[ms] = *(const short8*)(wk + (size_t)ms * 16 * 8);
            short8 bf = *(const short8*)(
                ybuf + (size_t)((q * 4 + kg) * 274 + ck * 16 + ln + k) * 8);
#pragma unroll
            for (int ms = 0; ms < 4; ++ms)
              acc[ms] = __builtin_amdgcn_mfma_f32_16x16x32_bf16(
                  af[ms], bf, acc[ms], 0, 0, 0);
          }
        }
        const int yc = ck * 16 + ln;
        const int w = w0 - 8 + yc;
        const bool wvalid = (unsigned)w < (unsigned)WLEN;
        const bool own = (yc >= 8 && yc < 264);
#pragma unroll
        for (int ms = 0; ms < 4; ++ms) {
          const int o0 = oh * 64 + ms * 16 + kg * 4;
          short4v pk;
#pragma unroll
          for (int rr = 0; rr < 4; ++rr) {
            int o = o0 + rr;
            float s = g1[o] * rsqrtf(rv1[o] + 1e-5f);
            float v = acc[ms][rr] * (r1v * s) +
                      ((r1v * b1[o] - rm1[o]) * s + be1[o]);
            v = v >= 0.f ? v : 0.1f * v;
            if (!wvalid) v = 0.f;
            if (own) rsum2 += v * fcw2[o];
            pk[rr] = f2bf(v);
          }
          held[i][ms] = pk;
        }
      }
    }
    __syncthreads();  // all xs reads done before y1s overwrites
#pragma unroll
    for (int i = 0; i < 5; ++i) {
      int t = wave + i * 8;
      if (t < 34) {
        const int oh = t & 1, ck = t >> 1;
        const int yc = ck * 16 + ln;
#pragma unroll
        for (int ms = 0; ms < 4; ++ms) {
          const int o0 = oh * 64 + ms * 16 + kg * 4;
          *(short4v*)(ybuf + (size_t)((o0 >> 3) * 272 + yc) * 8 + (o0 & 7)) =
              held[i][ms];
        }
      }
    }
    __syncthreads();  // y1s ready

    red[tid] = rsum2;
    __syncthreads();
    for (int s = 256; s > 0; s >>= 1) {
      if (tid < s) red[tid] += red[tid + s];
      __syncthreads();
    }
    if (tid == 0) {
      atomicExch(&racc2[bid], red[0]);
      __threadfence();
      atomicAdd(&ctrs[1], 1);
    }
  }

  // ---------------- phase C: conv2 ----------------
  {
    const int oq = wave & 3, wh = wave >> 2;
    float r2v = 0.f;
#pragma unroll
    for (int pass = 0; pass < 2; ++pass) {
      floatx4 acc[4][4];
#pragma unroll
      for (int ms = 0; ms < 4; ++ms)
#pragma unroll
        for (int ns = 0; ns < 4; ++ns) acc[ms][ns] = (floatx4){0.f, 0.f, 0.f, 0.f};

#pragma unroll
      for (int c = 0; c < 12; ++c) {
        const int qq = c / 3, k = c % 3;
        short8 af[4], bf[4];
        const short* wk =
            wp2 + ((size_t)(k * 16 + qq * 4 + kg) * 256 + oq * 64 + ln) * 8;
#pragma unroll
        for (int ms = 0; ms < 4; ++ms)
          af[ms] = *(const short8*)(wk + (size_t)ms * 16 * 8);
#pragma unroll
        for (int ns = 0; ns < 4; ++ns)
          bf[ns] = *(const short8*)(
              ybuf + (size_t)((qq * 4 + kg) * 272 +
                              wh * 128 + pass * 64 + ns * 16 + ln + k + 7) * 8);
#pragma unroll
        for (int ms = 0; ms < 4; ++ms)
#pragma unroll
          for (int ns = 0; ns < 4; ++ns)
            acc[ms][ns] = __builtin_amdgcn_mfma_f32_16x16x32_bf16(
                af[ms], bf[ns], acc[ms][ns], 0, 0, 0);
      }

      if (pass == 0) {
        // spin2: all racc2 posted (overlapped behind pass-0 MFMA)
        if (tid == 0) {
          for (int it = 0; it < 2000000; ++it)
            if (atomicAdd(&ctrs[1], 0) >= NBLK) break;
        }
        __syncthreads();
        __threadfence();
      }
      if (pass == 0 || true) {
        if (pass == 0) {
          float zs = 0.f;
#pragma unroll
          for (int t = 0; t < 8; ++t) zs += atomicAdd(&racc2[b * 8 + t], 0.0f);
          float z = zs * (1.f / (float)WLEN) + fcb2[0];
          r2v = 1.f / (1.f + expf(-z));
        }
      }

#pragma unroll
      for (int ms = 0; ms < 4; ++ms) {
        const int o0 = oq * 64 + ms * 16 + kg * 4;
        float a_[4], c_[4];
#pragma unroll
        for (int rr = 0; rr < 4; ++rr) {
          int o = o0 + rr;
          float s = g2[o] * rsqrtf(rv2[o] + 1e-5f);
          a_[rr] = r2v * s;
          c_[rr] = (r2v * b2[o] - rm2[o]) * s + be2[o];
        }
#pragma unroll
        for (int np = 0; np < 2; ++np) {  // ns pairs (0,1), (2,3)
          float m0[4], m1[4];
#pragma unroll
          for (int half = 0; half < 2; ++half) {
            int ns = np * 2 + half;
#pragma unroll
            for (int rr = 0; rr < 4; ++rr) {
              float v = acc[ms][ns][rr] * a_[rr] + c_[rr];
              v = v >= 0.f ? v : 0.1f * v;
              float m = fmaxf(v, __shfl_xor(v, 1));
              if (half == 0) m0[rr] = m; else m1[rr] = m;
            }
          }
          const int pc = (w0 >> 1) + wh * 64 + pass * 32 + np * 16 + ln;
#pragma unroll
          for (int rr = 0; rr < 4; ++rr) {
            int src = kg * 16 + ((ln & 7) << 1);
            float aa = __shfl(m0[rr], src);
            float bb = __shfl(m1[rr], src);
            float val = (ln < 8) ? aa : bb;
            out[((size_t)(b * 256 + o0 + rr)) * (WLEN / 2) + pc] = val;
          }
        }
      }
    }
  }
}

// ---------------------------------------------------------------------------
extern "C" void kernel_launch(void* const* d_in, const int* in_sizes, int n_in,
                              void* d_out, int out_size, void* d_ws, size_t ws_size,
                              hipStream_t stream) {
  const float* x    = (const float*)d_in[0];
  const float* w1   = (const float*)d_in[1];
  const float* b1   = (const float*)d_in[2];
  const float* fcw1 = (const float*)d_in[3];
  const float* fcb1 = (const float*)d_in[4];
  const float* g1   = (const float*)d_in[5];
  const float* be1  = (const float*)d_in[6];
  const float* rm1  = (const float*)d_in[7];
  const float* rv1  = (const float*)d_in[8];
  const float* w2   = (const float*)d_in[9];
  const float* b2   = (const float*)d_in[10];
  const float* fcw2 = (const float*)d_in[11];
  const float* fcb2 = (const float*)d_in[12];
  const float* g2   = (const float*)d_in[13];
  const float* be2  = (const float*)d_in[14];
  const float* rm2  = (const float*)d_in[15];
  const float* rv2  = (const float*)d_in[16];
  float* out = (float*)d_out;

  char* ws = (char*)d_ws;
  float* racc1 = (float*)ws;              // 1 KB
  float* racc2 = (float*)(ws + 1024);     // 1 KB
  int*   ctrs  = (int*)(ws + 2048);       // 8 B
  short* wp1   = (short*)(ws + 4096);     // 48 KB
  short* wp2   = (short*)(ws + 65536);    // 192 KB

  hipMemsetAsync(ctrs, 0, 8, stream);
  fused_all<<<dim3(8, 32), 512, 0, stream>>>(
      x, w1, b1, fcw1, fcb1, g1, be1, rm1, rv1,
      w2, b2, fcw2, fcb2, g2, be2, rm2, rv2,
      wp1, wp2, racc1, racc2, ctrs, out);
}

// Round 13
// 124.349 us; speedup vs baseline: 1.8567x; 1.8567x over previous
//
#include <hip/hip_runtime.h>
#include <hip/hip_bf16.h>
#include <math.h>

#define BATCH 32
#define WLEN  2048

typedef __attribute__((ext_vector_type(8))) short short8;
typedef __attribute__((ext_vector_type(4))) short short4v;
typedef __attribute__((ext_vector_type(4))) float floatx4;

// async global->LDS DMA, 16 B per lane; lds dest must be linear in lane.
#define GLOAD_LDS16(g, l)                                                     \
  __builtin_amdgcn_global_load_lds(                                           \
      (const __attribute__((address_space(1))) unsigned int*)(g),             \
      (__attribute__((address_space(3))) unsigned int*)(l), 16, 0, 0)

__device__ inline short f2bf(float f) {
  unsigned u = __float_as_uint(f);
  unsigned r = (u + 0x7fffu + ((u >> 16) & 1u)) >> 16;
  return (short)r;
}

// ---------------------------------------------------------------------------
// Kernel 1: conv1 + routing1 (device-sync) + routing2 partials + w2 packing.
// Grid (16,32) = 512 blocks x 512 thr = EXACT 2-blocks/CU residency
// (LDS 66.6 KB, VGPR <= 128) -> bounded spin is safe.
// Order per block: pack w1->LDS & stage x->LDS & rsum1 partial (no external
// deps) -> post racc1+ctr -> MFMA (self-contained) -> single-thread spin for
// all 512 posts (overlapped behind MFMA) -> r1 -> epilogue -> y1p + racc2.
// ---------------------------------------------------------------------------
__global__ __launch_bounds__(512, 4) void conv1_fused(
    const float* __restrict__ x, const float* __restrict__ w1,
    const float* __restrict__ b1, const float* __restrict__ fcw1,
    const float* __restrict__ fcb1, const float* __restrict__ g1,
    const float* __restrict__ be1, const float* __restrict__ rm1,
    const float* __restrict__ rv1, const float* __restrict__ fcw2,
    const float* __restrict__ w2, short* __restrict__ wp2,
    float* __restrict__ racc1, float* __restrict__ racc2,
    int* __restrict__ ctr, short* __restrict__ y1p) {
  const int jt = blockIdx.x;          // 0..15 (128-col tile)
  const int b  = blockIdx.y;          // 0..31
  const int bid = b * 16 + jt;        // 0..511
  const int w0 = jt * 128;
  const int tid = threadIdx.x;
  const int wave = tid >> 6, lane = tid & 63;
  const int ln = lane & 15, kg = lane >> 4;
  const int oh = wave & 1, wq = wave >> 1;

  __shared__ short wl[3 * 8 * 128 * 8];  // 48 KB   [k][ig][o][e]
  __shared__ short xs[8 * 130 * 8];      // 16.6 KB [ig][p][e]
  __shared__ float red[512];             // 2 KB

  // ---- pack w1 -> LDS (private, removes cross-block dep for MFMA) ----
  for (int i = tid; i < 3072; i += 512) {
    int o = i & 127;
    int t = i >> 7;
    int ig = t & 7;
    int k = t >> 3;
    short8 v;
#pragma unroll
    for (int e = 0; e < 8; ++e) v[e] = f2bf(w1[(o * 64 + ig * 8 + e) * 3 + k]);
    *(short8*)(wl + (size_t)i * 8) = v;
  }

  // ---- side job: 24 blocks pack w2 -> wp2 (consumed only by kernel 2) ----
  if (bid < 24) {
    int iw = bid * 512 + tid;           // 12288 items total
    int o = iw & 255;
    int t = iw >> 8;
    int ig = t & 15;
    int k = t >> 4;
    short8 v;
#pragma unroll
    for (int e = 0; e < 8; ++e) v[e] = f2bf(w2[(o * 128 + ig * 8 + e) * 3 + k]);
    *(short8*)(wp2 + (size_t)iw * 8) = v;
  }

  // ---- stage x tile (fp32 -> bf16, halo 1) + routing1 partial ----
  {
    const float* xb = x + (size_t)b * 64 * WLEN;
    float rsum = 0.f;
    for (int idx = tid; idx < 8 * 130; idx += 512) {
      int ig = idx / 130;
      int p = idx - ig * 130;
      int w = w0 - 1 + p;
      short8 v = {0, 0, 0, 0, 0, 0, 0, 0};
      if ((unsigned)w < (unsigned)WLEN) {
        const float* src = xb + (size_t)(ig * 8) * WLEN + w;
        float fv[8];
#pragma unroll
        for (int e = 0; e < 8; ++e) fv[e] = src[(size_t)e * WLEN];
#pragma unroll
        for (int e = 0; e < 8; ++e) v[e] = f2bf(fv[e]);
        if (p >= 1 && p <= 128) {
#pragma unroll
          for (int e = 0; e < 8; ++e) rsum += fv[e] * fcw1[ig * 8 + e];
        }
      }
      *(short8*)(xs + (size_t)idx * 8) = v;
    }
    red[tid] = rsum;
    __syncthreads();   // also publishes wl + xs to the block
    for (int s = 256; s > 0; s >>= 1) {
      if (tid < s) red[tid] += red[tid + s];
      __syncthreads();
    }
    if (tid == 0) {
      atomicExch(&racc1[bid], red[0]);
      __threadfence();
      atomicAdd(ctr, 1);
    }
  }

  // ---- MFMA (only reads own LDS) ----
  floatx4 acc[4][2];
#pragma unroll
  for (int ms = 0; ms < 4; ++ms)
#pragma unroll
    for (int ns = 0; ns < 2; ++ns) acc[ms][ns] = (floatx4){0.f, 0.f, 0.f, 0.f};

#pragma unroll
  for (int q = 0; q < 2; ++q) {
#pragma unroll
    for (int k = 0; k < 3; ++k) {
      short8 af[4], bf[2];
      const short* wk = wl + ((size_t)(k * 8 + q * 4 + kg) * 128 + oh * 64 + ln) * 8;
#pragma unroll
      for (int ms = 0; ms < 4; ++ms)
        af[ms] = *(const short8*)(wk + (size_t)ms * 16 * 8);
#pragma unroll
      for (int ns = 0; ns < 2; ++ns)
        bf[ns] = *(const short8*)(
            xs + ((q * 4 + kg) * 130 + wq * 32 + ns * 16 + ln + k) * 8);
#pragma unroll
      for (int ms = 0; ms < 4; ++ms)
#pragma unroll
        for (int ns = 0; ns < 2; ++ns)
          acc[ms][ns] = __builtin_amdgcn_mfma_f32_16x16x32_bf16(
              af[ms], bf[ns], acc[ms][ns], 0, 0, 0);
    }
  }

  // ---- spin (single thread, bounded) + r1 broadcast ----
  if (tid == 0) {
    for (int it = 0; it < 400000; ++it)
      if (atomicAdd(ctr, 0) >= 512) break;
    __threadfence();
    float zs = 0.f;
#pragma unroll
    for (int t = 0; t < 16; ++t) zs += atomicAdd(&racc1[b * 16 + t], 0.0f);
    float z = zs * (1.f / (float)WLEN) + fcb1[0];
    red[0] = 1.f / (1.f + expf(-z));
  }
  __syncthreads();
  const float r1v = red[0];
  __syncthreads();  // all reads of red[0] complete before red reuse

  // ---- epilogue: BN1 + leaky + y1 store (granule-dense) + routing2 ----
  float rsum2 = 0.f;
#pragma unroll
  for (int ms = 0; ms < 4; ++ms) {
    const int o0 = oh * 64 + ms * 16 + kg * 4;
    float a_[4], c_[4], fw[4];
#pragma unroll
    for (int rr = 0; rr < 4; ++rr) {
      int o = o0 + rr;
      float s = g1[o] * rsqrtf(rv1[o] + 1e-5f);
      a_[rr] = r1v * s;
      c_[rr] = (r1v * b1[o] - rm1[o]) * s + be1[o];
      fw[rr] = fcw2[o];
    }
#pragma unroll
    for (int ns = 0; ns < 2; ++ns) {
      int w = w0 + wq * 32 + ns * 16 + ln;
      short pk[4];
#pragma unroll
      for (int rr = 0; rr < 4; ++rr) {
        float v = acc[ms][ns][rr] * a_[rr] + c_[rr];
        v = v >= 0.f ? v : 0.1f * v;
        rsum2 += v * fw[rr];
        pk[rr] = f2bf(v);
      }
      unsigned u0 = (unsigned)(unsigned short)pk[0] |
                    ((unsigned)(unsigned short)pk[1] << 16);
      unsigned u1 = (unsigned)(unsigned short)pk[2] |
                    ((unsigned)(unsigned short)pk[3] << 16);
      unsigned p0 = __shfl_xor((int)u0, 16);
      unsigned p1 = __shfl_xor((int)u1, 16);
      if (!(kg & 1)) {
        int4 s8;
        s8.x = (int)u0; s8.y = (int)u1; s8.z = (int)p0; s8.w = (int)p1;
        // y1p layout [b][o/8][w][8]; o0 multiple of 8 here
        *(int4*)(y1p + ((size_t)(b * 16 + (o0 >> 3)) * WLEN + w) * 8) = s8;
      }
    }
  }
  red[tid] = rsum2;
  __syncthreads();
  for (int s = 256; s > 0; s >>= 1) {
    if (tid < s) red[tid] += red[tid + s];
    __syncthreads();
  }
  if (tid == 0) racc2[bid] = red[0];  // kernel boundary = sync for conv2
}

// ---------------------------------------------------------------------------
// Kernel 2: conv2 (R7's best-measured version, unchanged).
// y1p bf16 [b][ig16][w][8] -> out fp32 pooled (B,256,1024).
// 512 threads (8 waves), tile 256o x 128w; weight chunks double-buffered
// via global_load_lds. grid (16,32).
// ---------------------------------------------------------------------------
__global__ __launch_bounds__(512, 4) void conv2_mfma(
    const short* __restrict__ y1p, const short* __restrict__ wp2,
    const float* __restrict__ bias, const float* __restrict__ g,
    const float* __restrict__ be, const float* __restrict__ rm,
    const float* __restrict__ rv, const float* __restrict__ racc2,
    const float* __restrict__ fcb, float* __restrict__ out) {
  const int b = blockIdx.y;
  const int w0 = blockIdx.x * 128;
  const int tid = threadIdx.x;
  const int wave = tid >> 6, lane = tid & 63;
  const int ln = lane & 15, kg = lane >> 4;
  const int oq = wave & 3, wh = wave >> 2;

  __shared__ short xs[16 * 130 * 8];   // 33.3 KB
  __shared__ short wbuf[2][8192];      // 32 KB, chunk = [4ig][256o][8e]

  // issue weight chunk 0 DMA (1024 items, 2 per thread)
  {
    const int ib0 = wave * 64, ib1 = 512 + wave * 64;
    GLOAD_LDS16(wp2 + (size_t)(ib0 + lane) * 8, wbuf[0] + (size_t)ib0 * 8);
    GLOAD_LDS16(wp2 + (size_t)(ib1 + lane) * 8, wbuf[0] + (size_t)ib1 * 8);
  }

  // stage x tile
  const short* yb = y1p + (size_t)b * 16 * WLEN * 8;
  for (int idx = tid; idx < 16 * 130; idx += 512) {
    int ig = idx / 130;
    int p = idx - ig * 130;
    int w = w0 - 1 + p;
    short8 v = {0, 0, 0, 0, 0, 0, 0, 0};
    if ((unsigned)w < (unsigned)WLEN)
      v = *(const short8*)(yb + ((size_t)ig * WLEN + w) * 8);
    *(short8*)(xs + idx * 8) = v;
  }
  __syncthreads();

  floatx4 acc[4][4];
#pragma unroll
  for (int ms = 0; ms < 4; ++ms)
#pragma unroll
    for (int ns = 0; ns < 4; ++ns) acc[ms][ns] = (floatx4){0.f, 0.f, 0.f, 0.f};

#pragma unroll
  for (int c = 0; c < 12; ++c) {
    const int cur = c & 1;
    const int q = c / 3, k = c % 3;

    if (c < 11) {
      const int nq = (c + 1) / 3, nk = (c + 1) % 3;
      const short* src = wp2 + (size_t)(nk * 16 + nq * 4) * 256 * 8;
      const int ib0 = wave * 64, ib1 = 512 + wave * 64;
      GLOAD_LDS16(src + (size_t)(ib0 + lane) * 8, wbuf[cur ^ 1] + (size_t)ib0 * 8);
      GLOAD_LDS16(src + (size_t)(ib1 + lane) * 8, wbuf[cur ^ 1] + (size_t)ib1 * 8);
    }

    short8 af[4], bf[4];
#pragma unroll
    for (int ms = 0; ms < 4; ++ms)
      af[ms] = *(const short8*)(
          wbuf[cur] + (size_t)(kg * 256 + oq * 64 + ms * 16 + ln) * 8);
#pragma unroll
    for (int ns = 0; ns < 4; ++ns)
      bf[ns] = *(const short8*)(
          xs + ((q * 4 + kg) * 130 + wh * 64 + ns * 16 + ln + k) * 8);
#pragma unroll
    for (int ms = 0; ms < 4; ++ms)
#pragma unroll
      for (int ns = 0; ns < 4; ++ns)
        acc[ms][ns] = __builtin_amdgcn_mfma_f32_16x16x32_bf16(
            af[ms], bf[ns], acc[ms][ns], 0, 0, 0);

    __syncthreads();
  }

  // r2
  float zs = 0.f;
#pragma unroll
  for (int t = 0; t < 16; ++t) zs += racc2[b * 16 + t];
  float z = zs * (1.f / (float)WLEN) + fcb[0];
  float r2v = 1.f / (1.f + expf(-z));

#pragma unroll
  for (int ms = 0; ms < 4; ++ms) {
    const int o0 = oq * 64 + ms * 16 + kg * 4;
    float a_[4], c_[4];
#pragma unroll
    for (int rr = 0; rr < 4; ++rr) {
      int o = o0 + rr;
      float s = g[o] * rsqrtf(rv[o] + 1e-5f);
      a_[rr] = r2v * s;
      c_[rr] = (r2v * bias[o] - rm[o]) * s + be[o];
    }
#pragma unroll
    for (int np = 0; np < 2; ++np) {
      float m0[4], m1[4];
#pragma unroll
      for (int half = 0; half < 2; ++half) {
        int ns = np * 2 + half;
#pragma unroll
        for (int rr = 0; rr < 4; ++rr) {
          float v = acc[ms][ns][rr] * a_[rr] + c_[rr];
          v = v >= 0.f ? v : 0.1f * v;
          float m = fmaxf(v, __shfl_xor(v, 1));
          if (half == 0) m0[rr] = m; else m1[rr] = m;
        }
      }
      const int pc = (w0 >> 1) + wh * 32 + np * 16 + ln;
#pragma unroll
      for (int rr = 0; rr < 4; ++rr) {
        int src = kg * 16 + ((ln & 7) << 1);
        float aa = __shfl(m0[rr], src);
        float bb = __shfl(m1[rr], src);
        float val = (ln < 8) ? aa : bb;
        out[((size_t)(b * 256 + o0 + rr)) * (WLEN / 2) + pc] = val;
      }
    }
  }
}

// ---------------------------------------------------------------------------
extern "C" void kernel_launch(void* const* d_in, const int* in_sizes, int n_in,
                              void* d_out, int out_size, void* d_ws, size_t ws_size,
                              hipStream_t stream) {
  const float* x    = (const float*)d_in[0];
  const float* w1   = (const float*)d_in[1];
  const float* b1   = (const float*)d_in[2];
  const float* fcw1 = (const float*)d_in[3];
  const float* fcb1 = (const float*)d_in[4];
  const float* g1   = (const float*)d_in[5];
  const float* be1  = (const float*)d_in[6];
  const float* rm1  = (const float*)d_in[7];
  const float* rv1  = (const float*)d_in[8];
  const float* w2   = (const float*)d_in[9];
  const float* b2   = (const float*)d_in[10];
  const float* fcw2 = (const float*)d_in[11];
  const float* fcb2 = (const float*)d_in[12];
  const float* g2   = (const float*)d_in[13];
  const float* be2  = (const float*)d_in[14];
  const float* rm2  = (const float*)d_in[15];
  const float* rv2  = (const float*)d_in[16];
  float* out = (float*)d_out;

  char* ws = (char*)d_ws;
  int*   ctr   = (int*)ws;                 // 4 B (memset each call)
  float* racc1 = (float*)(ws + 1024);      // 2 KB
  float* racc2 = (float*)(ws + 3072);      // 2 KB
  short* wp2   = (short*)(ws + 8192);      // 192 KB
  short* y1p   = (short*)(ws + (size_t)1024 * 1024);  // 16 MiB

  hipMemsetAsync(ctr, 0, 4, stream);
  conv1_fused<<<dim3(16, 32), 512, 0, stream>>>(
      x, w1, b1, fcw1, fcb1, g1, be1, rm1, rv1, fcw2,
      w2, wp2, racc1, racc2, ctr, y1p);
  conv2_mfma<<<dim3(16, 32), 512, 0, stream>>>(
      y1p, wp2, b2, g2, be2, rm2, rv2, racc2, fcb2, out);
}

// Round 14
// 71.498 us; speedup vs baseline: 3.2291x; 1.7392x over previous
//
#include <hip/hip_runtime.h>
#include <hip/hip_bf16.h>
#include <math.h>

#define BATCH 32
#define WLEN  2048

typedef __attribute__((ext_vector_type(8))) short short8;
typedef __attribute__((ext_vector_type(4))) short short4v;
typedef __attribute__((ext_vector_type(4))) float floatx4;

// async global->LDS DMA, 16 B per lane; lds dest must be linear in lane.
#define GLOAD_LDS16(g, l)                                                     \
  __builtin_amdgcn_global_load_lds(                                           \
      (const __attribute__((address_space(1))) unsigned int*)(g),             \
      (__attribute__((address_space(3))) unsigned int*)(l), 16, 0, 0)

#define SENT 0xFFFFFFFFu   // NaN bit pattern; finite partial sums never match

__device__ inline short f2bf(float f) {
  unsigned u = __float_as_uint(f);
  unsigned r = (u + 0x7fffu + ((u >> 16) & 1u)) >> 16;
  return (short)r;
}

// ---------------------------------------------------------------------------
// Kernel 1: conv1 + routing1 (sentinel sync, zero RMW) + routing2 partials +
// w2 packing. Grid (16,32) = 512 blocks x 512 thr = exact 2-blocks/CU
// residency (LDS 66.6 KB) -> bounded poll is safe.
// Per block: pack w1->LDS; stage x->LDS + rsum1; reduce; POST racc1[bid]
// (relaxed atomic store); MFMA (own LDS only, overlaps other blocks' posts);
// single-thread sentinel-poll of 16 slots (plain coherent loads); r1;
// epilogue -> y1p + racc2.
// ---------------------------------------------------------------------------
__global__ __launch_bounds__(512, 4) void conv1_fused(
    const float* __restrict__ x, const float* __restrict__ w1,
    const float* __restrict__ b1, const float* __restrict__ fcw1,
    const float* __restrict__ fcb1, const float* __restrict__ g1,
    const float* __restrict__ be1, const float* __restrict__ rm1,
    const float* __restrict__ rv1, const float* __restrict__ fcw2,
    const float* __restrict__ w2, short* __restrict__ wp2,
    float* __restrict__ racc1, float* __restrict__ racc2,
    short* __restrict__ y1p) {
  const int jt = blockIdx.x;          // 0..15 (128-col tile)
  const int b  = blockIdx.y;          // 0..31
  const int bid = b * 16 + jt;        // 0..511
  const int w0 = jt * 128;
  const int tid = threadIdx.x;
  const int wave = tid >> 6, lane = tid & 63;
  const int ln = lane & 15, kg = lane >> 4;
  const int oh = wave & 1, wq = wave >> 1;

  __shared__ short wl[3 * 8 * 128 * 8];  // 48 KB   [k][ig][o][e]
  __shared__ short xs[8 * 130 * 8];      // 16.6 KB [ig][p][e]
  __shared__ float red[512];             // 2 KB

  // ---- pack w1 -> LDS (private per block; no cross-block dependency) ----
  for (int i = tid; i < 3072; i += 512) {
    int o = i & 127;
    int t = i >> 7;
    int ig = t & 7;
    int k = t >> 3;
    short8 v;
#pragma unroll
    for (int e = 0; e < 8; ++e) v[e] = f2bf(w1[(o * 64 + ig * 8 + e) * 3 + k]);
    *(short8*)(wl + (size_t)i * 8) = v;
  }

  // ---- side job: 24 blocks pack w2 -> wp2 (consumed only by kernel 2) ----
  if (bid < 24) {
    int iw = bid * 512 + tid;           // 12288 items total
    int o = iw & 255;
    int t = iw >> 8;
    int ig = t & 15;
    int k = t >> 4;
    short8 v;
#pragma unroll
    for (int e = 0; e < 8; ++e) v[e] = f2bf(w2[(o * 128 + ig * 8 + e) * 3 + k]);
    *(short8*)(wp2 + (size_t)iw * 8) = v;
  }

  // ---- stage x tile (fp32 -> bf16, halo 1) + routing1 partial ----
  {
    const float* xb = x + (size_t)b * 64 * WLEN;
    float rsum = 0.f;
    for (int idx = tid; idx < 8 * 130; idx += 512) {
      int ig = idx / 130;
      int p = idx - ig * 130;
      int w = w0 - 1 + p;
      short8 v = {0, 0, 0, 0, 0, 0, 0, 0};
      if ((unsigned)w < (unsigned)WLEN) {
        const float* src = xb + (size_t)(ig * 8) * WLEN + w;
        float fv[8];
#pragma unroll
        for (int e = 0; e < 8; ++e) fv[e] = src[(size_t)e * WLEN];
#pragma unroll
        for (int e = 0; e < 8; ++e) v[e] = f2bf(fv[e]);
        if (p >= 1 && p <= 128) {
#pragma unroll
          for (int e = 0; e < 8; ++e) rsum += fv[e] * fcw1[ig * 8 + e];
        }
      }
      *(short8*)(xs + (size_t)idx * 8) = v;
    }
    red[tid] = rsum;
    __syncthreads();   // publishes wl + xs to the block too
    for (int s = 256; s > 0; s >>= 1) {
      if (tid < s) red[tid] += red[tid + s];
      __syncthreads();
    }
    if (tid == 0) {
      // POST: one relaxed device-scope atomic store; no RMW anywhere.
      __hip_atomic_store(&racc1[bid], red[0], __ATOMIC_RELAXED,
                         __HIP_MEMORY_SCOPE_AGENT);
    }
  }

  // ---- MFMA (only reads own LDS; overlaps other blocks' staging/posts) ----
  floatx4 acc[4][2];
#pragma unroll
  for (int ms = 0; ms < 4; ++ms)
#pragma unroll
    for (int ns = 0; ns < 2; ++ns) acc[ms][ns] = (floatx4){0.f, 0.f, 0.f, 0.f};

#pragma unroll
  for (int q = 0; q < 2; ++q) {
#pragma unroll
    for (int k = 0; k < 3; ++k) {
      short8 af[4], bf[2];
      const short* wk = wl + ((size_t)(k * 8 + q * 4 + kg) * 128 + oh * 64 + ln) * 8;
#pragma unroll
      for (int ms = 0; ms < 4; ++ms)
        af[ms] = *(const short8*)(wk + (size_t)ms * 16 * 8);
#pragma unroll
      for (int ns = 0; ns < 2; ++ns)
        bf[ns] = *(const short8*)(
            xs + ((q * 4 + kg) * 130 + wq * 32 + ns * 16 + ln + k) * 8);
#pragma unroll
      for (int ms = 0; ms < 4; ++ms)
#pragma unroll
        for (int ns = 0; ns < 2; ++ns)
          acc[ms][ns] = __builtin_amdgcn_mfma_f32_16x16x32_bf16(
              af[ms], bf[ns], acc[ms][ns], 0, 0, 0);
    }
  }

  // ---- sentinel poll (single thread, plain coherent loads, bounded) ----
  if (tid == 0) {
    float zs = 0.f;
#pragma unroll
    for (int t = 0; t < 16; ++t) {
      const unsigned* slot = (const unsigned*)&racc1[b * 16 + t];
      unsigned uv = __hip_atomic_load(slot, __ATOMIC_RELAXED,
                                      __HIP_MEMORY_SCOPE_AGENT);
      for (int it = 0; it < 1000000 && uv == SENT; ++it) {
        __builtin_amdgcn_s_sleep(1);
        uv = __hip_atomic_load(slot, __ATOMIC_RELAXED,
                               __HIP_MEMORY_SCOPE_AGENT);
      }
      zs += __uint_as_float(uv);
    }
    float z = zs * (1.f / (float)WLEN) + fcb1[0];
    red[0] = 1.f / (1.f + expf(-z));
  }
  __syncthreads();
  const float r1v = red[0];
  __syncthreads();  // reads of red[0] complete before red reuse

  // ---- epilogue: BN1 + leaky + y1 store (granule-dense) + routing2 ----
  float rsum2 = 0.f;
#pragma unroll
  for (int ms = 0; ms < 4; ++ms) {
    const int o0 = oh * 64 + ms * 16 + kg * 4;
    float a_[4], c_[4], fw[4];
#pragma unroll
    for (int rr = 0; rr < 4; ++rr) {
      int o = o0 + rr;
      float s = g1[o] * rsqrtf(rv1[o] + 1e-5f);
      a_[rr] = r1v * s;
      c_[rr] = (r1v * b1[o] - rm1[o]) * s + be1[o];
      fw[rr] = fcw2[o];
    }
#pragma unroll
    for (int ns = 0; ns < 2; ++ns) {
      int w = w0 + wq * 32 + ns * 16 + ln;
      short pk[4];
#pragma unroll
      for (int rr = 0; rr < 4; ++rr) {
        float v = acc[ms][ns][rr] * a_[rr] + c_[rr];
        v = v >= 0.f ? v : 0.1f * v;
        rsum2 += v * fw[rr];
        pk[rr] = f2bf(v);
      }
      unsigned u0 = (unsigned)(unsigned short)pk[0] |
                    ((unsigned)(unsigned short)pk[1] << 16);
      unsigned u1 = (unsigned)(unsigned short)pk[2] |
                    ((unsigned)(unsigned short)pk[3] << 16);
      unsigned p0 = __shfl_xor((int)u0, 16);
      unsigned p1 = __shfl_xor((int)u1, 16);
      if (!(kg & 1)) {
        int4 s8;
        s8.x = (int)u0; s8.y = (int)u1; s8.z = (int)p0; s8.w = (int)p1;
        // y1p layout [b][o/8][w][8]; o0 multiple of 8 here
        *(int4*)(y1p + ((size_t)(b * 16 + (o0 >> 3)) * WLEN + w) * 8) = s8;
      }
    }
  }
  red[tid] = rsum2;
  __syncthreads();
  for (int s = 256; s > 0; s >>= 1) {
    if (tid < s) red[tid] += red[tid + s];
    __syncthreads();
  }
  if (tid == 0) racc2[bid] = red[0];  // kernel boundary = sync for conv2
}

// ---------------------------------------------------------------------------
// Kernel 2: conv2 (unchanged, known-good).
// y1p bf16 [b][ig16][w][8] -> out fp32 pooled (B,256,1024).
// 512 threads (8 waves), tile 256o x 128w; weight chunks double-buffered
// via global_load_lds. grid (16,32).
// ---------------------------------------------------------------------------
__global__ __launch_bounds__(512, 4) void conv2_mfma(
    const short* __restrict__ y1p, const short* __restrict__ wp2,
    const float* __restrict__ bias, const float* __restrict__ g,
    const float* __restrict__ be, const float* __restrict__ rm,
    const float* __restrict__ rv, const float* __restrict__ racc2,
    const float* __restrict__ fcb, float* __restrict__ out) {
  const int b = blockIdx.y;
  const int w0 = blockIdx.x * 128;
  const int tid = threadIdx.x;
  const int wave = tid >> 6, lane = tid & 63;
  const int ln = lane & 15, kg = lane >> 4;
  const int oq = wave & 3, wh = wave >> 2;

  __shared__ short xs[16 * 130 * 8];   // 33.3 KB
  __shared__ short wbuf[2][8192];      // 32 KB, chunk = [4ig][256o][8e]

  // issue weight chunk 0 DMA (1024 items, 2 per thread)
  {
    const int ib0 = wave * 64, ib1 = 512 + wave * 64;
    GLOAD_LDS16(wp2 + (size_t)(ib0 + lane) * 8, wbuf[0] + (size_t)ib0 * 8);
    GLOAD_LDS16(wp2 + (size_t)(ib1 + lane) * 8, wbuf[0] + (size_t)ib1 * 8);
  }

  // stage x tile
  const short* yb = y1p + (size_t)b * 16 * WLEN * 8;
  for (int idx = tid; idx < 16 * 130; idx += 512) {
    int ig = idx / 130;
    int p = idx - ig * 130;
    int w = w0 - 1 + p;
    short8 v = {0, 0, 0, 0, 0, 0, 0, 0};
    if ((unsigned)w < (unsigned)WLEN)
      v = *(const short8*)(yb + ((size_t)ig * WLEN + w) * 8);
    *(short8*)(xs + idx * 8) = v;
  }
  __syncthreads();

  floatx4 acc[4][4];
#pragma unroll
  for (int ms = 0; ms < 4; ++ms)
#pragma unroll
    for (int ns = 0; ns < 4; ++ns) acc[ms][ns] = (floatx4){0.f, 0.f, 0.f, 0.f};

#pragma unroll
  for (int c = 0; c < 12; ++c) {
    const int cur = c & 1;
    const int q = c / 3, k = c % 3;

    if (c < 11) {
      const int nq = (c + 1) / 3, nk = (c + 1) % 3;
      const short* src = wp2 + (size_t)(nk * 16 + nq * 4) * 256 * 8;
      const int ib0 = wave * 64, ib1 = 512 + wave * 64;
      GLOAD_LDS16(src + (size_t)(ib0 + lane) * 8, wbuf[cur ^ 1] + (size_t)ib0 * 8);
      GLOAD_LDS16(src + (size_t)(ib1 + lane) * 8, wbuf[cur ^ 1] + (size_t)ib1 * 8);
    }

    short8 af[4], bf[4];
#pragma unroll
    for (int ms = 0; ms < 4; ++ms)
      af[ms] = *(const short8*)(
          wbuf[cur] + (size_t)(kg * 256 + oq * 64 + ms * 16 + ln) * 8);
#pragma unroll
    for (int ns = 0; ns < 4; ++ns)
      bf[ns] = *(const short8*)(
          xs + ((q * 4 + kg) * 130 + wh * 64 + ns * 16 + ln + k) * 8);
#pragma unroll
    for (int ms = 0; ms < 4; ++ms)
#pragma unroll
      for (int ns = 0; ns < 4; ++ns)
        acc[ms][ns] = __builtin_amdgcn_mfma_f32_16x16x32_bf16(
            af[ms], bf[ns], acc[ms][ns], 0, 0, 0);

    __syncthreads();
  }

  // r2
  float zs = 0.f;
#pragma unroll
  for (int t = 0; t < 16; ++t) zs += racc2[b * 16 + t];
  float z = zs * (1.f / (float)WLEN) + fcb[0];
  float r2v = 1.f / (1.f + expf(-z));

#pragma unroll
  for (int ms = 0; ms < 4; ++ms) {
    const int o0 = oq * 64 + ms * 16 + kg * 4;
    float a_[4], c_[4];
#pragma unroll
    for (int rr = 0; rr < 4; ++rr) {
      int o = o0 + rr;
      float s = g[o] * rsqrtf(rv[o] + 1e-5f);
      a_[rr] = r2v * s;
      c_[rr] = (r2v * bias[o] - rm[o]) * s + be[o];
    }
#pragma unroll
    for (int np = 0; np < 2; ++np) {
      float m0[4], m1[4];
#pragma unroll
      for (int half = 0; half < 2; ++half) {
        int ns = np * 2 + half;
#pragma unroll
        for (int rr = 0; rr < 4; ++rr) {
          float v = acc[ms][ns][rr] * a_[rr] + c_[rr];
          v = v >= 0.f ? v : 0.1f * v;
          float m = fmaxf(v, __shfl_xor(v, 1));
          if (half == 0) m0[rr] = m; else m1[rr] = m;
        }
      }
      const int pc = (w0 >> 1) + wh * 32 + np * 16 + ln;
#pragma unroll
      for (int rr = 0; rr < 4; ++rr) {
        int src = kg * 16 + ((ln & 7) << 1);
        float aa = __shfl(m0[rr], src);
        float bb = __shfl(m1[rr], src);
        float val = (ln < 8) ? aa : bb;
        out[((size_t)(b * 256 + o0 + rr)) * (WLEN / 2) + pc] = val;
      }
    }
  }
}

// ---------------------------------------------------------------------------
extern "C" void kernel_launch(void* const* d_in, const int* in_sizes, int n_in,
                              void* d_out, int out_size, void* d_ws, size_t ws_size,
                              hipStream_t stream) {
  const float* x    = (const float*)d_in[0];
  const float* w1   = (const float*)d_in[1];
  const float* b1   = (const float*)d_in[2];
  const float* fcw1 = (const float*)d_in[3];
  const float* fcb1 = (const float*)d_in[4];
  const float* g1   = (const float*)d_in[5];
  const float* be1  = (const float*)d_in[6];
  const float* rm1  = (const float*)d_in[7];
  const float* rv1  = (const float*)d_in[8];
  const float* w2   = (const float*)d_in[9];
  const float* b2   = (const float*)d_in[10];
  const float* fcw2 = (const float*)d_in[11];
  const float* fcb2 = (const float*)d_in[12];
  const float* g2   = (const float*)d_in[13];
  const float* be2  = (const float*)d_in[14];
  const float* rm2  = (const float*)d_in[15];
  const float* rv2  = (const float*)d_in[16];
  float* out = (float*)d_out;

  char* ws = (char*)d_ws;
  float* racc1 = (float*)ws;               // 2 KB (sentinel-armed each launch)
  float* racc2 = (float*)(ws + 2048);      // 2 KB
  short* wp2   = (short*)(ws + 8192);      // 192 KB
  short* y1p   = (short*)(ws + (size_t)1024 * 1024);  // 16 MiB

  hipMemsetAsync(racc1, 0xFF, 2048, stream);  // arm sentinels
  conv1_fused<<<dim3(16, 32), 512, 0, stream>>>(
      x, w1, b1, fcw1, fcb1, g1, be1, rm1, rv1, fcw2,
      w2, wp2, racc1, racc2, y1p);
  conv2_mfma<<<dim3(16, 32), 512, 0, stream>>>(
      y1p, wp2, b2, g2, be2, rm2, rv2, racc2, fcb2, out);
}

// Round 15
// 55.571 us; speedup vs baseline: 4.1545x; 1.2866x over previous
//
#include <hip/hip_runtime.h>
#include <hip/hip_bf16.h>
#include <math.h>

#define BATCH 32
#define WLEN  2048

typedef __attribute__((ext_vector_type(8))) short short8;
typedef __attribute__((ext_vector_type(4))) short short4v;
typedef __attribute__((ext_vector_type(4))) float floatx4;

// async global->LDS DMA, 16 B per lane; lds dest must be linear in lane.
#define GLOAD_LDS16(g, l)                                                     \
  __builtin_amdgcn_global_load_lds(                                           \
      (const __attribute__((address_space(1))) unsigned int*)(g),             \
      (__attribute__((address_space(3))) unsigned int*)(l), 16, 0, 0)

__device__ inline short f2bf(float f) {
  unsigned u = __float_as_uint(f);
  unsigned r = (u + 0x7fffu + ((u >> 16) & 1u)) >> 16;
  return (short)r;
}

// ---------------------------------------------------------------------------
// fused prep: blocks 0..11 pack w1 -> wp1[k][ig8][o128][8]
//             blocks 12..59 pack w2 -> wp2[k][ig16][o256][8]
//             blocks 60..315 routing1 partials racc1[b*8+j]
// ---------------------------------------------------------------------------
__global__ __launch_bounds__(256) void fused_prep(
    const float* __restrict__ w1, const float* __restrict__ w2,
    const float* __restrict__ x, const float* __restrict__ fcw1,
    short* __restrict__ wp1, short* __restrict__ wp2,
    float* __restrict__ racc1) {
  const int blk = blockIdx.x;
  const int tid = threadIdx.x;
  if (blk < 12) {
    int iw = blk * 256 + tid;          // (k, ig, o) over 3*8*128
    int o = iw & 127;
    int t = iw >> 7;
    int ig = t & 7;
    int k = t >> 3;
    short8 v;
#pragma unroll
    for (int e = 0; e < 8; ++e) v[e] = f2bf(w1[(o * 64 + ig * 8 + e) * 3 + k]);
    *(short8*)(wp1 + (size_t)iw * 8) = v;
  } else if (blk < 60) {
    int iw = (blk - 12) * 256 + tid;   // (k, ig, o) over 3*16*256
    int o = iw & 255;
    int t = iw >> 8;
    int ig = t & 15;
    int k = t >> 4;
    short8 v;
#pragma unroll
    for (int e = 0; e < 8; ++e) v[e] = f2bf(w2[(o * 128 + ig * 8 + e) * 3 + k]);
    *(short8*)(wp2 + (size_t)iw * 8) = v;
  } else {
    int t = blk - 60;
    int j = t & 7, b = t >> 3;
    const float4* xb = (const float4*)(x + ((size_t)b * 64 + j * 8) * WLEN);
    float sum = 0.f;
    for (int idx = tid; idx < 8 * 512; idx += 256) {
      int c = idx >> 9;
      float4 v = xb[idx];
      sum += (v.x + v.y + v.z + v.w) * fcw1[j * 8 + c];
    }
    __shared__ float red[256];
    red[tid] = sum;
    __syncthreads();
    for (int s = 128; s > 0; s >>= 1) {
      if (tid < s) red[tid] += red[tid + s];
      __syncthreads();
    }
    if (tid == 0) racc1[b * 8 + j] = red[0];
  }
}

// ---------------------------------------------------------------------------
// conv1: x fp32 (B,64,W) -> y1p bf16 [b][o/8][w][8], + routing2 partials.
// 512 threads (8 waves), tile 128o x 128w; wave = 64o x 32w (4ms x 2ns).
// Weights (48KB) LDS-resident via global_load_lds; y1 stores granule-dense
// (kg-pair merge -> 16B int4 per even lane). grid (16,32).
// ---------------------------------------------------------------------------
__global__ __launch_bounds__(512, 4) void conv1_mfma(
    const float* __restrict__ x, const short* __restrict__ wp1,
    const float* __restrict__ bias, const float* __restrict__ g,
    const float* __restrict__ be, const float* __restrict__ rm,
    const float* __restrict__ rv, const float* __restrict__ racc1,
    const float* __restrict__ fcb, const float* __restrict__ fcw2,
    short* __restrict__ y1p, float* __restrict__ racc2) {
  const int b = blockIdx.y;
  const int w0 = blockIdx.x * 128;
  const int tid = threadIdx.x;
  const int wave = tid >> 6, lane = tid & 63;
  const int ln = lane & 15, kg = lane >> 4;
  const int oh = wave & 1, wq = wave >> 1;

  __shared__ short wl[3 * 8 * 128 * 8];  // 48 KB, [k][ig][o][e]
  __shared__ short xs[8 * 130 * 8];      // 16.6 KB, [ig][p][e]
  __shared__ float red[512];             // 2 KB

  // stage weights via async DMA: 3072 16B items, 6 per thread
#pragma unroll
  for (int c = 0; c < 6; ++c) {
    const int ib = c * 512 + wave * 64;  // wave-uniform item base
    GLOAD_LDS16(wp1 + (size_t)(ib + lane) * 8, wl + (size_t)ib * 8);
  }

  // stage x tile (fp32 -> bf16), halo of 1
  const float* xb = x + (size_t)b * 64 * WLEN;
  for (int idx = tid; idx < 8 * 130; idx += 512) {
    int ig = idx / 130;
    int p = idx - ig * 130;
    int w = w0 - 1 + p;
    short8 v = {0, 0, 0, 0, 0, 0, 0, 0};
    if ((unsigned)w < (unsigned)WLEN) {
      const float* src = xb + (size_t)(ig * 8) * WLEN + w;
#pragma unroll
      for (int e = 0; e < 8; ++e) v[e] = f2bf(src[(size_t)e * WLEN]);
    }
    *(short8*)(xs + idx * 8) = v;
  }
  __syncthreads();

  floatx4 acc[4][2];
#pragma unroll
  for (int ms = 0; ms < 4; ++ms)
#pragma unroll
    for (int ns = 0; ns < 2; ++ns) acc[ms][ns] = (floatx4){0.f, 0.f, 0.f, 0.f};

#pragma unroll
  for (int q = 0; q < 2; ++q) {
#pragma unroll
    for (int k = 0; k < 3; ++k) {
      short8 af[4], bf[2];
      const short* wk = wl + ((size_t)(k * 8 + q * 4 + kg) * 128 + oh * 64 + ln) * 8;
#pragma unroll
      for (int ms = 0; ms < 4; ++ms)
        af[ms] = *(const short8*)(wk + (size_t)ms * 16 * 8);
#pragma unroll
      for (int ns = 0; ns < 2; ++ns)
        bf[ns] = *(const short8*)(
            xs + ((q * 4 + kg) * 130 + wq * 32 + ns * 16 + ln + k) * 8);
#pragma unroll
      for (int ms = 0; ms < 4; ++ms)
#pragma unroll
        for (int ns = 0; ns < 2; ++ns)
          acc[ms][ns] = __builtin_amdgcn_mfma_f32_16x16x32_bf16(
              af[ms], bf[ns], acc[ms][ns], 0, 0, 0);
    }
  }

  // r1 (racc1 complete: kernel boundary)
  float zs = 0.f;
#pragma unroll
  for (int qq = 0; qq < 8; ++qq) zs += racc1[b * 8 + qq];
  float z = zs * (1.f / (float)WLEN) + fcb[0];
  float r1v = 1.f / (1.f + expf(-z));

  float rsum2 = 0.f;
#pragma unroll
  for (int ms = 0; ms < 4; ++ms) {
    const int o0 = oh * 64 + ms * 16 + kg * 4;
    float a_[4], c_[4], fw[4];
#pragma unroll
    for (int rr = 0; rr < 4; ++rr) {
      int o = o0 + rr;
      float s = g[o] * rsqrtf(rv[o] + 1e-5f);
      a_[rr] = r1v * s;
      c_[rr] = (r1v * bias[o] - rm[o]) * s + be[o];
      fw[rr] = fcw2[o];
    }
#pragma unroll
    for (int ns = 0; ns < 2; ++ns) {
      int w = w0 + wq * 32 + ns * 16 + ln;
      short pk[4];
#pragma unroll
      for (int rr = 0; rr < 4; ++rr) {
        float v = acc[ms][ns][rr] * a_[rr] + c_[rr];
        v = v >= 0.f ? v : 0.1f * v;
        rsum2 += v * fw[rr];
        pk[rr] = f2bf(v);
      }
      // pack + merge with kg^1 partner -> 16B granule-dense store
      unsigned u0 = (unsigned)(unsigned short)pk[0] |
                    ((unsigned)(unsigned short)pk[1] << 16);
      unsigned u1 = (unsigned)(unsigned short)pk[2] |
                    ((unsigned)(unsigned short)pk[3] << 16);
      unsigned p0 = __shfl_xor((int)u0, 16);
      unsigned p1 = __shfl_xor((int)u1, 16);
      if (!(kg & 1)) {
        int4 s8;
        s8.x = (int)u0; s8.y = (int)u1; s8.z = (int)p0; s8.w = (int)p1;
        *(int4*)(y1p + ((size_t)(b * 16 + (o0 >> 3)) * WLEN + w) * 8) = s8;
      }
    }
  }
  red[tid] = rsum2;
  __syncthreads();
  for (int s = 256; s > 0; s >>= 1) {
    if (tid < s) red[tid] += red[tid + s];
    __syncthreads();
  }
  if (tid == 0) racc2[b * 16 + blockIdx.x] = red[0];
}

// ---------------------------------------------------------------------------
// conv2 SPLIT-COUT: y1p bf16 [b][ig16][w][8] -> out fp32 pooled (B,256,1024).
// grid (16,32,2): blockIdx.z = Cout half. Block = 128o x 128w, 512 thr;
// wave (oq2 = wave&1, wq = wave>>1) = 64o x 32w (4ms x 2ns, acc 32 VGPR).
// Weights direct from L2; NO barriers in K loop; 4 blocks/CU = 32 waves/CU.
// ---------------------------------------------------------------------------
__global__ __launch_bounds__(512, 4) void conv2_mfma(
    const short* __restrict__ y1p, const short* __restrict__ wp2,
    const float* __restrict__ bias, const float* __restrict__ g,
    const float* __restrict__ be, const float* __restrict__ rm,
    const float* __restrict__ rv, const float* __restrict__ racc2,
    const float* __restrict__ fcb, float* __restrict__ out) {
  const int b = blockIdx.y;
  const int w0 = blockIdx.x * 128;
  const int ohh = blockIdx.z;          // Cout half: 0 or 1
  const int tid = threadIdx.x;
  const int wave = tid >> 6, lane = tid & 63;
  const int ln = lane & 15, kg = lane >> 4;
  const int oq2 = wave & 1, wq = wave >> 1;

  __shared__ short xs[16 * 130 * 8];   // 33.3 KB

  // stage x tile (once)
  const short* yb = y1p + (size_t)b * 16 * WLEN * 8;
  for (int idx = tid; idx < 16 * 130; idx += 512) {
    int ig = idx / 130;
    int p = idx - ig * 130;
    int w = w0 - 1 + p;
    short8 v = {0, 0, 0, 0, 0, 0, 0, 0};
    if ((unsigned)w < (unsigned)WLEN)
      v = *(const short8*)(yb + ((size_t)ig * WLEN + w) * 8);
    *(short8*)(xs + idx * 8) = v;
  }
  __syncthreads();

  floatx4 acc[4][2];
#pragma unroll
  for (int ms = 0; ms < 4; ++ms)
#pragma unroll
    for (int ns = 0; ns < 2; ++ns) acc[ms][ns] = (floatx4){0.f, 0.f, 0.f, 0.f};

#pragma unroll
  for (int c = 0; c < 12; ++c) {
    const int q = c / 3, k = c % 3;
    short8 af[4], bf[2];
    const short* wk = wp2 + ((size_t)(k * 16 + q * 4 + kg) * 256 +
                             ohh * 128 + oq2 * 64 + ln) * 8;
#pragma unroll
    for (int ms = 0; ms < 4; ++ms)
      af[ms] = *(const short8*)(wk + (size_t)ms * 16 * 8);
#pragma unroll
    for (int ns = 0; ns < 2; ++ns)
      bf[ns] = *(const short8*)(
          xs + ((q * 4 + kg) * 130 + wq * 32 + ns * 16 + ln + k) * 8);
#pragma unroll
    for (int ms = 0; ms < 4; ++ms)
#pragma unroll
      for (int ns = 0; ns < 2; ++ns)
        acc[ms][ns] = __builtin_amdgcn_mfma_f32_16x16x32_bf16(
            af[ms], bf[ns], acc[ms][ns], 0, 0, 0);
  }

  // r2 (racc2 complete: kernel boundary)
  float zs = 0.f;
#pragma unroll
  for (int t = 0; t < 16; ++t) zs += racc2[b * 16 + t];
  float z = zs * (1.f / (float)WLEN) + fcb[0];
  float r2v = 1.f / (1.f + expf(-z));

#pragma unroll
  for (int ms = 0; ms < 4; ++ms) {
    const int o0 = ohh * 128 + oq2 * 64 + ms * 16 + kg * 4;
    float a_[4], c_[4];
#pragma unroll
    for (int rr = 0; rr < 4; ++rr) {
      int o = o0 + rr;
      float s = g[o] * rsqrtf(rv[o] + 1e-5f);
      a_[rr] = r2v * s;
      c_[rr] = (r2v * bias[o] - rm[o]) * s + be[o];
    }
    float m0[4], m1[4];
#pragma unroll
    for (int half = 0; half < 2; ++half) {
#pragma unroll
      for (int rr = 0; rr < 4; ++rr) {
        float v = acc[ms][half][rr] * a_[rr] + c_[rr];
        v = v >= 0.f ? v : 0.1f * v;
        float m = fmaxf(v, __shfl_xor(v, 1));
        if (half == 0) m0[rr] = m; else m1[rr] = m;
      }
    }
    const int pc = (w0 >> 1) + wq * 16 + ln;
#pragma unroll
    for (int rr = 0; rr < 4; ++rr) {
      int src = kg * 16 + ((ln & 7) << 1);
      float aa = __shfl(m0[rr], src);
      float bb = __shfl(m1[rr], src);
      float val = (ln < 8) ? aa : bb;
      out[((size_t)(b * 256 + o0 + rr)) * (WLEN / 2) + pc] = val;
    }
  }
}

// ---------------------------------------------------------------------------
extern "C" void kernel_launch(void* const* d_in, const int* in_sizes, int n_in,
                              void* d_out, int out_size, void* d_ws, size_t ws_size,
                              hipStream_t stream) {
  const float* x    = (const float*)d_in[0];
  const float* w1   = (const float*)d_in[1];
  const float* b1   = (const float*)d_in[2];
  const float* fcw1 = (const float*)d_in[3];
  const float* fcb1 = (const float*)d_in[4];
  const float* g1   = (const float*)d_in[5];
  const float* be1  = (const float*)d_in[6];
  const float* rm1  = (const float*)d_in[7];
  const float* rv1  = (const float*)d_in[8];
  const float* w2   = (const float*)d_in[9];
  const float* b2   = (const float*)d_in[10];
  const float* fcw2 = (const float*)d_in[11];
  const float* fcb2 = (const float*)d_in[12];
  const float* g2   = (const float*)d_in[13];
  const float* be2  = (const float*)d_in[14];
  const float* rm2  = (const float*)d_in[15];
  const float* rv2  = (const float*)d_in[16];
  float* out = (float*)d_out;

  char* ws = (char*)d_ws;
  short* y1p   = (short*)ws;                          // 32*16*2048*8*2 = 16 MiB
  short* wp1   = (short*)(ws + (size_t)16 * 1024 * 1024);            // 48 KiB
  short* wp2   = (short*)(ws + (size_t)16 * 1024 * 1024 + 65536);    // 192 KiB
  float* racc1 = (float*)(ws + (size_t)16 * 1024 * 1024 + 327680);   // 256 f
  float* racc2 = racc1 + 256;                                        // 512 f

  fused_prep<<<316, 256, 0, stream>>>(w1, w2, x, fcw1, wp1, wp2, racc1);
  conv1_mfma<<<dim3(16, 32), 512, 0, stream>>>(
      x, wp1, b1, g1, be1, rm1, rv1, racc1, fcb1, fcw2, y1p, racc2);
  conv2_mfma<<<dim3(16, 32, 2), 512, 0, stream>>>(
      y1p, wp2, b2, g2, be2, rm2, rv2, racc2, fcb2, out);
}